// Round 1
// baseline (920.003 us; speedup 1.0000x reference)
//
#include <hip/hip_runtime.h>

// Problem constants: B=256, C=512, H=W=28, NCLS=20
#define BATCH 256
#define CH    512
#define HW    784          // 28*28
#define HW4   196          // float4s per (b,c) row
#define NROWS (BATCH * CH) // 131072
#define NCLS  20
#define RPW   16           // rows per wave: 131072 rows / (2048 blk * 4 waves) = 16

// Kernel 1: persistent fat blocks; each 64-lane wave owns 16 consecutive
// (b,c) rows. Per row: stream 196 float4s of x (pooled sum) and fmap
// (scale by reweight, write out_map). Wave-only shuffle reduction —
// no LDS, no __syncthreads, no block-level epilogue.
__global__ __launch_bounds__(256) void fused_pool_mul(
    const float* __restrict__ x, const float* __restrict__ fmap,
    const int*   __restrict__ label, const float* __restrict__ W,
    float* __restrict__ pooled, float* __restrict__ out_map)
{
    const int lane = threadIdx.x & 63;
    const int gw   = blockIdx.x * 4 + (threadIdx.x >> 6);  // global wave id, 0..8191
    const int row0 = gw * RPW;                             // first row of this wave
    const int b    = row0 >> 9;                            // wave-uniform (16 | 512)

    // Multi-hot label mask, built once per wave (label values are 0/1).
    unsigned mask = 0u;
#pragma unroll
    for (int k = 0; k < NCLS; ++k)
        mask |= (unsigned)(label[b * NCLS + k] != 0) << k;

    for (int r = 0; r < RPW; ++r) {
        const int row = row0 + r;
        const int c   = row & 511;

        // reweight scalar: sum of selected W rows at column c (L1-hot, uniform)
        float rw = 0.0f;
#pragma unroll
        for (int k = 0; k < NCLS; ++k) {
            float w = W[k * CH + c];
            rw += ((mask >> k) & 1u) ? w : 0.0f;
        }

        const long long base = (long long)row * HW;
        const float4* x4 = (const float4*)(x    + base);
        const float4* f4 = (const float4*)(fmap + base);
        float4*       o4 = (float4*)(out_map + base);

        // 196 = 3*64 + 4: three full passes + 4-lane tail. Issue all loads
        // up front for MLP (up to 8 x 16B in flight per lane).
        float4 xa = x4[lane];
        float4 xb = x4[lane + 64];
        float4 xc = x4[lane + 128];
        float4 fa = f4[lane];
        float4 fb = f4[lane + 64];
        float4 fc = f4[lane + 128];
        float4 xt = make_float4(0.f, 0.f, 0.f, 0.f);
        float4 ft = make_float4(0.f, 0.f, 0.f, 0.f);
        if (lane < 4) {
            xt = x4[192 + lane];
            ft = f4[192 + lane];
        }

        float s = ((xa.x + xa.y) + (xa.z + xa.w))
                + ((xb.x + xb.y) + (xb.z + xb.w))
                + ((xc.x + xc.y) + (xc.z + xc.w))
                + ((xt.x + xt.y) + (xt.z + xt.w));

        float4 oa = make_float4(fa.x * rw, fa.y * rw, fa.z * rw, fa.w * rw);
        float4 ob = make_float4(fb.x * rw, fb.y * rw, fb.z * rw, fb.w * rw);
        float4 oc = make_float4(fc.x * rw, fc.y * rw, fc.z * rw, fc.w * rw);
        o4[lane]       = oa;
        o4[lane + 64]  = ob;
        o4[lane + 128] = oc;
        if (lane < 4) {
            float4 ot = make_float4(ft.x * rw, ft.y * rw, ft.z * rw, ft.w * rw);
            o4[192 + lane] = ot;
        }

        // Wave-wide sum (64 lanes), no LDS.
#pragma unroll
        for (int off = 32; off > 0; off >>= 1)
            s += __shfl_down(s, off, 64);
        if (lane == 0)
            pooled[row] = s * (1.0f / (float)HW);
    }
}

// Kernel 2: logits[b,n] = dot(pooled[b,:], W[n,:]) + bias[n]
// One 64-lane wave per batch row; pooled row held in 8 regs/lane.
__global__ __launch_bounds__(64) void logits_kernel(
    const float* __restrict__ pooled, const float* __restrict__ W,
    const float* __restrict__ bias, float* __restrict__ logits)
{
    const int b    = blockIdx.x;
    const int lane = threadIdx.x;

    float p[8];
#pragma unroll
    for (int i = 0; i < 8; ++i)
        p[i] = pooled[b * CH + lane + i * 64];

    for (int n = 0; n < NCLS; ++n) {
        float s = 0.0f;
#pragma unroll
        for (int i = 0; i < 8; ++i)
            s += p[i] * W[n * CH + lane + i * 64];
#pragma unroll
        for (int off = 32; off > 0; off >>= 1)
            s += __shfl_down(s, off, 64);
        if (lane == 0)
            logits[b * NCLS + n] = s + bias[n];
    }
}

extern "C" void kernel_launch(void* const* d_in, const int* in_sizes, int n_in,
                              void* d_out, int out_size, void* d_ws, size_t ws_size,
                              hipStream_t stream) {
    const float* x     = (const float*)d_in[0];   // [256,512,28,28]
    const float* fmap  = (const float*)d_in[1];   // [256,512,28,28]
    const int*   label = (const int*)  d_in[2];   // [256,20]
    const float* W     = (const float*)d_in[3];   // [20,512]
    const float* bias  = (const float*)d_in[4];   // [20]

    float* logits  = (float*)d_out;                    // [256,20]
    float* out_map = (float*)d_out + BATCH * NCLS;     // [256,512,28,28]
    float* pooled  = (float*)d_ws;                     // [256,512] = 512 KB scratch

    // 2048 blocks x 256 threads = 8192 waves; 16 rows/wave covers 131072 rows
    // exactly; 8 blocks/CU x 4 waves fills all 32 wave slots per CU.
    fused_pool_mul<<<2048, 256, 0, stream>>>(x, fmap, label, W, pooled, out_map);
    logits_kernel<<<BATCH, 64, 0, stream>>>(pooled, W, bias, logits);
}